// Round 1
// baseline (447.802 us; speedup 1.0000x reference)
//
#include <hip/hip_runtime.h>
#include <math.h>

#define H 1024
#define V 50257
#define L 512

__device__ __forceinline__ float wave_sum(float v) {
#pragma unroll
    for (int off = 32; off; off >>= 1) v += __shfl_xor(v, off, 64);
    return v;
}
__device__ __forceinline__ float wave_max(float v) {
#pragma unroll
    for (int off = 32; off; off >>= 1) v = fmaxf(v, __shfl_xor(v, off, 64));
    return v;
}
__device__ __forceinline__ float sigmoidf(float x) { return 1.f / (1.f + expf(-x)); }

// ---- K1: attn_logits[l] = dot(cat(emb, h0), W_attn[l]) + b_attn[l], l in [0,L)
__global__ void k_attn_logits(const int* __restrict__ inp, const float* __restrict__ h0,
                              const float* __restrict__ emb_table,
                              const float* __restrict__ W_attn, const float* __restrict__ b_attn,
                              float* __restrict__ logits) {
    int wave = (blockIdx.x * blockDim.x + threadIdx.x) >> 6;
    int lane = threadIdx.x & 63;
    if (wave >= L) return;
    const float* emb = emb_table + (size_t)inp[0] * H;
    const float* wrow = W_attn + (size_t)wave * (2 * H);
    float acc = 0.f;
#pragma unroll
    for (int it = 0; it < 8; ++it) {
        int k = it * 256 + lane * 4;
        float4 wv = *(const float4*)(wrow + k);
        const float* src = (k < H) ? (emb + k) : (h0 + (k - H));
        float4 xv = *(const float4*)src;
        acc += wv.x * xv.x + wv.y * xv.y + wv.z * xv.z + wv.w * xv.w;
    }
    acc = wave_sum(acc);
    if (lane == 0) logits[wave] = acc + b_attn[wave];
}

// ---- K2: softmax over L logits -> attn_w (also zero ws_aa for K3's atomics)
__global__ void k_softmax(const float* __restrict__ logits, float* __restrict__ attn_w,
                          float* __restrict__ ws_aa) {
    __shared__ float sh[8];
    __shared__ float bc;
    int t = threadIdx.x, lane = t & 63, wid = t >> 6;
    float v = logits[t];
    float m = wave_max(v);
    if (lane == 0) sh[wid] = m;
    __syncthreads();
    if (t == 0) { float mm = sh[0]; for (int i = 1; i < 8; ++i) mm = fmaxf(mm, sh[i]); bc = mm; }
    __syncthreads();
    m = bc;
    float e = expf(v - m);
    float s = wave_sum(e);
    __syncthreads();
    if (lane == 0) sh[wid] = s;
    __syncthreads();
    if (t == 0) { float ss = 0.f; for (int i = 0; i < 8; ++i) ss += sh[i]; bc = ss; }
    __syncthreads();
    attn_w[t] = e / bc;
    ws_aa[t] = 0.f;
    ws_aa[t + 512] = 0.f;
}

// ---- K3: attn_applied[j] = sum_l w[l] * enc[l][j]  (partial rows per block + atomics)
__global__ void k_attn_applied(const float* __restrict__ attn_w, const float* __restrict__ enc,
                               float* __restrict__ ws_aa) {
    int b = blockIdx.x, t = threadIdx.x;  // 64 blocks x 256 threads; block does 8 rows, thread does float4 col t
    float4 acc = make_float4(0.f, 0.f, 0.f, 0.f);
#pragma unroll
    for (int r = 0; r < 8; ++r) {
        int l = b * 8 + r;
        float w = attn_w[l];
        float4 e = *(const float4*)(enc + (size_t)l * H + t * 4);
        acc.x += w * e.x; acc.y += w * e.y; acc.z += w * e.z; acc.w += w * e.w;
    }
    atomicAdd(&ws_aa[t * 4 + 0], acc.x);
    atomicAdd(&ws_aa[t * 4 + 1], acc.y);
    atomicAdd(&ws_aa[t * 4 + 2], acc.z);
    atomicAdd(&ws_aa[t * 4 + 3], acc.w);
}

// ---- K4: x[r] = relu(dot(cat(emb, attn_applied), W_comb[r]) + b_comb[r]), r in [0,H)
__global__ void k_comb(const int* __restrict__ inp, const float* __restrict__ emb_table,
                       const float* __restrict__ ws_aa, const float* __restrict__ W_comb,
                       const float* __restrict__ b_comb, float* __restrict__ ws_x) {
    int wave = (blockIdx.x * blockDim.x + threadIdx.x) >> 6;
    int lane = threadIdx.x & 63;
    if (wave >= H) return;
    const float* emb = emb_table + (size_t)inp[0] * H;
    const float* wrow = W_comb + (size_t)wave * (2 * H);
    float acc = 0.f;
#pragma unroll
    for (int it = 0; it < 8; ++it) {
        int k = it * 256 + lane * 4;
        float4 wv = *(const float4*)(wrow + k);
        const float* src = (k < H) ? (emb + k) : (ws_aa + (k - H));
        float4 xv = *(const float4*)src;
        acc += wv.x * xv.x + wv.y * xv.y + wv.z * xv.z + wv.w * xv.w;
    }
    acc = wave_sum(acc);
    if (lane == 0) ws_x[wave] = fmaxf(acc + b_comb[wave], 0.f);
}

// ---- K5: gates[r] = dot(x, W_ih[r]) + dot(h0, W_hh[r]) + b_ih[r] + b_hh[r], r in [0,4H)
__global__ void k_gates(const float* __restrict__ ws_x, const float* __restrict__ h0,
                        const float* __restrict__ W_ih, const float* __restrict__ W_hh,
                        const float* __restrict__ b_ih, const float* __restrict__ b_hh,
                        float* __restrict__ gates) {
    int wave = (blockIdx.x * blockDim.x + threadIdx.x) >> 6;
    int lane = threadIdx.x & 63;
    if (wave >= 4 * H) return;
    const float* wi = W_ih + (size_t)wave * H;
    const float* wh = W_hh + (size_t)wave * H;
    float acc = 0.f;
#pragma unroll
    for (int it = 0; it < 4; ++it) {
        int k = it * 256 + lane * 4;
        float4 a = *(const float4*)(wi + k);
        float4 xv = *(const float4*)(ws_x + k);
        acc += a.x * xv.x + a.y * xv.y + a.z * xv.z + a.w * xv.w;
        float4 b = *(const float4*)(wh + k);
        float4 hv = *(const float4*)(h0 + k);
        acc += b.x * hv.x + b.y * hv.y + b.z * hv.z + b.w * hv.w;
    }
    acc = wave_sum(acc);
    if (lane == 0) gates[wave] = acc + b_ih[wave] + b_hh[wave];
}

// ---- K6: LSTM elementwise -> h1, c1
__global__ void k_lstm(const float* __restrict__ gates, const float* __restrict__ c0,
                       float* __restrict__ out_h1, float* __restrict__ out_c1) {
    int j = threadIdx.x;  // block of 1024
    float ig = sigmoidf(gates[j]);
    float fg = sigmoidf(gates[j + H]);
    float gg = tanhf(gates[j + 2 * H]);
    float og = sigmoidf(gates[j + 3 * H]);
    float c1 = fg * c0[j] + ig * gg;
    float h1 = og * tanhf(c1);
    out_c1[j] = c1;
    out_h1[j] = h1;
}

// ---- K7: logits[v] = dot(h1, W_out[v]) + b_out[v], v in [0,V)   (the 206 MB matvec)
__global__ void k_out(const float* __restrict__ h1, const float* __restrict__ W_out,
                      const float* __restrict__ b_out, float* __restrict__ logp) {
    int wave = (blockIdx.x * blockDim.x + threadIdx.x) >> 6;
    int lane = threadIdx.x & 63;
    if (wave >= V) return;
    const float* wrow = W_out + (size_t)wave * H;
    float acc = 0.f;
#pragma unroll
    for (int it = 0; it < 4; ++it) {
        int k = it * 256 + lane * 4;
        float4 wv = *(const float4*)(wrow + k);
        float4 hv = *(const float4*)(h1 + k);
        acc += wv.x * hv.x + wv.y * hv.y + wv.z * hv.z + wv.w * hv.w;
    }
    acc = wave_sum(acc);
    if (lane == 0) logp[wave] = acc + b_out[wave];
}

// ---- K8: in-place log-softmax over V
__global__ void k_logsoftmax(float* __restrict__ logp) {
    __shared__ float sh[16];
    __shared__ float bc;
    int t = threadIdx.x, lane = t & 63, wid = t >> 6;
    float m = -1e30f;
    for (int v = t; v < V; v += 1024) m = fmaxf(m, logp[v]);
    m = wave_max(m);
    if (lane == 0) sh[wid] = m;
    __syncthreads();
    if (t == 0) { float mm = sh[0]; for (int i = 1; i < 16; ++i) mm = fmaxf(mm, sh[i]); bc = mm; }
    __syncthreads();
    m = bc;
    float s = 0.f;
    for (int v = t; v < V; v += 1024) s += expf(logp[v] - m);
    s = wave_sum(s);
    __syncthreads();
    if (lane == 0) sh[wid] = s;
    __syncthreads();
    if (t == 0) { float ss = 0.f; for (int i = 0; i < 16; ++i) ss += sh[i]; bc = m + logf(ss); }
    __syncthreads();
    float lse = bc;
    for (int v = t; v < V; v += 1024) logp[v] -= lse;
}

extern "C" void kernel_launch(void* const* d_in, const int* in_sizes, int n_in,
                              void* d_out, int out_size, void* d_ws, size_t ws_size,
                              hipStream_t stream) {
    const int*   inp     = (const int*)d_in[0];
    const float* h0      = (const float*)d_in[1];
    const float* c0      = (const float*)d_in[2];
    const float* enc     = (const float*)d_in[3];
    const float* emb     = (const float*)d_in[4];
    const float* W_attn  = (const float*)d_in[5];
    const float* b_attn  = (const float*)d_in[6];
    const float* W_comb  = (const float*)d_in[7];
    const float* b_comb  = (const float*)d_in[8];
    const float* W_ih    = (const float*)d_in[9];
    const float* W_hh    = (const float*)d_in[10];
    const float* b_ih    = (const float*)d_in[11];
    const float* b_hh    = (const float*)d_in[12];
    const float* W_out   = (const float*)d_in[13];
    const float* b_out   = (const float*)d_in[14];

    float* out      = (float*)d_out;
    float* out_logp = out;                  // V
    float* out_h1   = out + V;              // H
    float* out_c1   = out + V + H;          // H
    float* out_attn = out + V + 2 * H;      // L

    float* ws        = (float*)d_ws;
    float* ws_logits = ws;                  // L
    float* ws_aa     = ws + 512;            // H
    float* ws_x      = ws + 512 + 1024;     // H
    float* ws_gates  = ws + 512 + 2048;     // 4H

    k_attn_logits<<<128, 256, 0, stream>>>(inp, h0, emb, W_attn, b_attn, ws_logits);
    k_softmax<<<1, 512, 0, stream>>>(ws_logits, out_attn, ws_aa);
    k_attn_applied<<<64, 256, 0, stream>>>(out_attn, enc, ws_aa);
    k_comb<<<256, 256, 0, stream>>>(inp, emb, ws_aa, W_comb, b_comb, ws_x);
    k_gates<<<1024, 256, 0, stream>>>(ws_x, h0, W_ih, W_hh, b_ih, b_hh, ws_gates);
    k_lstm<<<1, 1024, 0, stream>>>(ws_gates, c0, out_h1, out_c1);
    k_out<<<(V + 3) / 4, 256, 0, stream>>>(out_h1, W_out, b_out, out_logp);
    k_logsoftmax<<<1, 1024, 0, stream>>>(out_logp);
}

// Round 2
// 433.675 us; speedup vs baseline: 1.0326x; 1.0326x over previous
//
#include <hip/hip_runtime.h>
#include <math.h>

#define H 1024
#define V 50257
#define L 512
#define RBLK 64   // reduction blocks for log-softmax

__device__ __forceinline__ float wave_sum(float v) {
#pragma unroll
    for (int off = 32; off; off >>= 1) v += __shfl_xor(v, off, 64);
    return v;
}
__device__ __forceinline__ float wave_max(float v) {
#pragma unroll
    for (int off = 32; off; off >>= 1) v = fmaxf(v, __shfl_xor(v, off, 64));
    return v;
}
__device__ __forceinline__ float sigmoidf(float x) { return 1.f / (1.f + expf(-x)); }

// ---- K1: attn_logits[l] = dot(cat(emb, h0), W_attn[l]) + b_attn[l]
__global__ void k_attn_logits(const int* __restrict__ inp, const float* __restrict__ h0,
                              const float* __restrict__ emb_table,
                              const float* __restrict__ W_attn, const float* __restrict__ b_attn,
                              float* __restrict__ logits) {
    int wave = (blockIdx.x * blockDim.x + threadIdx.x) >> 6;
    int lane = threadIdx.x & 63;
    if (wave >= L) return;
    const float* emb = emb_table + (size_t)inp[0] * H;
    const float* wrow = W_attn + (size_t)wave * (2 * H);
    float acc = 0.f;
#pragma unroll
    for (int it = 0; it < 8; ++it) {
        int k = it * 256 + lane * 4;
        float4 wv = *(const float4*)(wrow + k);
        const float* src = (k < H) ? (emb + k) : (h0 + (k - H));
        float4 xv = *(const float4*)src;
        acc += wv.x * xv.x + wv.y * xv.y + wv.z * xv.z + wv.w * xv.w;
    }
    acc = wave_sum(acc);
    if (lane == 0) logits[wave] = acc + b_attn[wave];
}

// ---- K2: softmax over L logits -> attn_w (also zero ws_aa for K3's atomics)
__global__ void k_softmax(const float* __restrict__ logits, float* __restrict__ attn_w,
                          float* __restrict__ ws_aa) {
    __shared__ float sh[8];
    __shared__ float bc;
    int t = threadIdx.x, lane = t & 63, wid = t >> 6;
    float v = logits[t];
    float m = wave_max(v);
    if (lane == 0) sh[wid] = m;
    __syncthreads();
    if (t == 0) { float mm = sh[0]; for (int i = 1; i < 8; ++i) mm = fmaxf(mm, sh[i]); bc = mm; }
    __syncthreads();
    m = bc;
    float e = expf(v - m);
    float s = wave_sum(e);
    __syncthreads();
    if (lane == 0) sh[wid] = s;
    __syncthreads();
    if (t == 0) { float ss = 0.f; for (int i = 0; i < 8; ++i) ss += sh[i]; bc = ss; }
    __syncthreads();
    attn_w[t] = e / bc;
    ws_aa[t] = 0.f;
    ws_aa[t + 512] = 0.f;
}

// ---- K3: attn_applied[j] = sum_l w[l] * enc[l][j]
__global__ void k_attn_applied(const float* __restrict__ attn_w, const float* __restrict__ enc,
                               float* __restrict__ ws_aa) {
    int b = blockIdx.x, t = threadIdx.x;  // 64 blocks x 256 threads
    float4 acc = make_float4(0.f, 0.f, 0.f, 0.f);
#pragma unroll
    for (int r = 0; r < 8; ++r) {
        int l = b * 8 + r;
        float w = attn_w[l];
        float4 e = *(const float4*)(enc + (size_t)l * H + t * 4);
        acc.x += w * e.x; acc.y += w * e.y; acc.z += w * e.z; acc.w += w * e.w;
    }
    atomicAdd(&ws_aa[t * 4 + 0], acc.x);
    atomicAdd(&ws_aa[t * 4 + 1], acc.y);
    atomicAdd(&ws_aa[t * 4 + 2], acc.z);
    atomicAdd(&ws_aa[t * 4 + 3], acc.w);
}

// ---- K4: x[r] = relu(dot(cat(emb, attn_applied), W_comb[r]) + b_comb[r])
__global__ void k_comb(const int* __restrict__ inp, const float* __restrict__ emb_table,
                       const float* __restrict__ ws_aa, const float* __restrict__ W_comb,
                       const float* __restrict__ b_comb, float* __restrict__ ws_x) {
    int wave = (blockIdx.x * blockDim.x + threadIdx.x) >> 6;
    int lane = threadIdx.x & 63;
    if (wave >= H) return;
    const float* emb = emb_table + (size_t)inp[0] * H;
    const float* wrow = W_comb + (size_t)wave * (2 * H);
    float acc = 0.f;
#pragma unroll
    for (int it = 0; it < 8; ++it) {
        int k = it * 256 + lane * 4;
        float4 wv = *(const float4*)(wrow + k);
        const float* src = (k < H) ? (emb + k) : (ws_aa + (k - H));
        float4 xv = *(const float4*)src;
        acc += wv.x * xv.x + wv.y * xv.y + wv.z * xv.z + wv.w * xv.w;
    }
    acc = wave_sum(acc);
    if (lane == 0) ws_x[wave] = fmaxf(acc + b_comb[wave], 0.f);
}

// ---- K5 (fused gates + LSTM): block j -> hidden element j; wave w -> gate row w*H+j
__global__ void k_gates_lstm(const float* __restrict__ ws_x, const float* __restrict__ h0,
                             const float* __restrict__ c0,
                             const float* __restrict__ W_ih, const float* __restrict__ W_hh,
                             const float* __restrict__ b_ih, const float* __restrict__ b_hh,
                             float* __restrict__ out_h1, float* __restrict__ out_c1) {
    __shared__ float g[4];
    int j = blockIdx.x;
    int wv = threadIdx.x >> 6;   // 0..3 = i,f,g,o
    int lane = threadIdx.x & 63;
    int row = wv * H + j;
    const float* wi = W_ih + (size_t)row * H;
    const float* wh = W_hh + (size_t)row * H;
    float acc = 0.f;
#pragma unroll
    for (int it = 0; it < 4; ++it) {
        int k = it * 256 + lane * 4;
        float4 a = *(const float4*)(wi + k);
        float4 xv = *(const float4*)(ws_x + k);
        acc += a.x * xv.x + a.y * xv.y + a.z * xv.z + a.w * xv.w;
        float4 b = *(const float4*)(wh + k);
        float4 hv = *(const float4*)(h0 + k);
        acc += b.x * hv.x + b.y * hv.y + b.z * hv.z + b.w * hv.w;
    }
    acc = wave_sum(acc);
    if (lane == 0) g[wv] = acc + b_ih[row] + b_hh[row];
    __syncthreads();
    if (threadIdx.x == 0) {
        float ig = sigmoidf(g[0]);
        float fg = sigmoidf(g[1]);
        float gg = tanhf(g[2]);
        float og = sigmoidf(g[3]);
        float c1 = fg * c0[j] + ig * gg;
        out_c1[j] = c1;
        out_h1[j] = og * tanhf(c1);
    }
}

// ---- K6: logits[v] = dot(h1, W_out[v]) + b_out[v]  (the 206 MB matvec)
__global__ void k_out(const float* __restrict__ h1, const float* __restrict__ W_out,
                      const float* __restrict__ b_out, float* __restrict__ logp) {
    int wave = (blockIdx.x * blockDim.x + threadIdx.x) >> 6;
    int lane = threadIdx.x & 63;
    if (wave >= V) return;
    const float* wrow = W_out + (size_t)wave * H;
    float acc = 0.f;
#pragma unroll
    for (int it = 0; it < 4; ++it) {
        int k = it * 256 + lane * 4;
        float4 wv = *(const float4*)(wrow + k);
        float4 hv = *(const float4*)(h1 + k);
        acc += wv.x * hv.x + wv.y * hv.y + wv.z * hv.z + wv.w * hv.w;
    }
    acc = wave_sum(acc);
    if (lane == 0) logp[wave] = acc + b_out[wave];
}

// ---- K7: parallel partial reduce for log-softmax: per-block (max, sumexp)
__global__ void k_red(const float* __restrict__ logp, float* __restrict__ pair) {
    __shared__ float sh[4];
    int t = threadIdx.x, lane = t & 63, wid = t >> 6;
    float vals[4];
    int n = 0;
    float m = -1e30f;
    for (int v = blockIdx.x * 256 + t; v < V; v += RBLK * 256) {
        vals[n] = logp[v];
        m = fmaxf(m, vals[n]);
        ++n;
    }
    m = wave_max(m);
    if (lane == 0) sh[wid] = m;
    __syncthreads();
    float m4 = fmaxf(fmaxf(sh[0], sh[1]), fmaxf(sh[2], sh[3]));
    float s = 0.f;
    for (int i = 0; i < n; ++i) s += expf(vals[i] - m4);
    s = wave_sum(s);
    __syncthreads();
    if (lane == 0) sh[wid] = s;
    __syncthreads();
    if (t == 0) {
        pair[blockIdx.x * 2]     = m4;
        pair[blockIdx.x * 2 + 1] = sh[0] + sh[1] + sh[2] + sh[3];
    }
}

// ---- K8: combine pairs (redundantly per thread) + grid-wide subtract
__global__ void k_sub(float* __restrict__ logp, const float* __restrict__ pair) {
    float mg = -1e30f;
#pragma unroll
    for (int i = 0; i < RBLK; ++i) mg = fmaxf(mg, pair[2 * i]);
    float sg = 0.f;
#pragma unroll
    for (int i = 0; i < RBLK; ++i) sg += pair[2 * i + 1] * expf(pair[2 * i] - mg);
    float lse = mg + logf(sg);
    int v = blockIdx.x * blockDim.x + threadIdx.x;
    if (v < V) logp[v] -= lse;
}

extern "C" void kernel_launch(void* const* d_in, const int* in_sizes, int n_in,
                              void* d_out, int out_size, void* d_ws, size_t ws_size,
                              hipStream_t stream) {
    const int*   inp     = (const int*)d_in[0];
    const float* h0      = (const float*)d_in[1];
    const float* c0      = (const float*)d_in[2];
    const float* enc     = (const float*)d_in[3];
    const float* emb     = (const float*)d_in[4];
    const float* W_attn  = (const float*)d_in[5];
    const float* b_attn  = (const float*)d_in[6];
    const float* W_comb  = (const float*)d_in[7];
    const float* b_comb  = (const float*)d_in[8];
    const float* W_ih    = (const float*)d_in[9];
    const float* W_hh    = (const float*)d_in[10];
    const float* b_ih    = (const float*)d_in[11];
    const float* b_hh    = (const float*)d_in[12];
    const float* W_out   = (const float*)d_in[13];
    const float* b_out   = (const float*)d_in[14];

    float* out      = (float*)d_out;
    float* out_logp = out;                  // V
    float* out_h1   = out + V;              // H
    float* out_c1   = out + V + H;          // H
    float* out_attn = out + V + 2 * H;      // L

    float* ws        = (float*)d_ws;
    float* ws_logits = ws;                  // L
    float* ws_aa     = ws + 512;            // H
    float* ws_x      = ws + 512 + 1024;     // H
    float* ws_pair   = ws + 512 + 2048;     // 2*RBLK

    k_attn_logits<<<128, 256, 0, stream>>>(inp, h0, emb, W_attn, b_attn, ws_logits);
    k_softmax<<<1, 512, 0, stream>>>(ws_logits, out_attn, ws_aa);
    k_attn_applied<<<64, 256, 0, stream>>>(out_attn, enc, ws_aa);
    k_comb<<<256, 256, 0, stream>>>(inp, emb, ws_aa, W_comb, b_comb, ws_x);
    k_gates_lstm<<<1024, 256, 0, stream>>>(ws_x, h0, c0, W_ih, W_hh, b_ih, b_hh, out_h1, out_c1);
    k_out<<<(V + 3) / 4, 256, 0, stream>>>(out_h1, W_out, b_out, out_logp);
    k_red<<<RBLK, 256, 0, stream>>>(out_logp, ws_pair);
    k_sub<<<(V + 255) / 256, 256, 0, stream>>>(out_logp, ws_pair);
}